// Round 13
// baseline (329.966 us; speedup 1.0000x reference)
//
#include <hip/hip_runtime.h>
#include <hip/hip_bf16.h>
#include <cstdint>
#include <cstddef>

// Problem constants
#define BB    4
#define NN    4096
#define DIM   1024
#define HEADS 16
#define DH    64
#define DIN   1024        // HEADS*DH
#define NQO   3072        // 3*DIN
#define MTOT  (BB*NN)     // 16384
#define KDIM  1024
#define EPS_F 1e-12f

using bf16 = __hip_bfloat16;
typedef __attribute__((ext_vector_type(8))) short bf16x8;
typedef __attribute__((ext_vector_type(4))) float f32x4;

// ---------------------------------------------------------------- helpers
__device__ __forceinline__ void gload_lds16(const void* g, void* l) {
    __builtin_amdgcn_global_load_lds(
        (const __attribute__((address_space(1))) void*)g,
        (__attribute__((address_space(3))) void*)l,
        16, 0, 0);
}

__device__ __forceinline__ ushort bf16_bits(float x) {
    union { bf16 h; ushort u; } c;
    c.h = __float2bfloat16(x);
    return c.u;
}

__device__ __forceinline__ float b2f(ushort u) {
    union { unsigned u32; float f; } c;
    c.u32 = ((unsigned)u) << 16;
    return c.f;
}

// ---------------------------------------------------------------- fused prologue:
// blocks [0,16384): RMSNorm row; [16384,19456): cast w_qkv; [19456,20480): cast w_out;
// [20480,20512): zero ss.
__global__ __launch_bounds__(256) void k_prologue(const float* __restrict__ x,
                                                  const float* __restrict__ gamma,
                                                  bf16* __restrict__ xn,
                                                  const float* __restrict__ wq,
                                                  bf16* __restrict__ wq_bf,
                                                  const float* __restrict__ wo,
                                                  bf16* __restrict__ wo_bf,
                                                  float* __restrict__ ss) {
    int blk = blockIdx.x;
    int t = threadIdx.x;
    if (blk < 16384) {
        int row = blk;
        const float4* xr = (const float4*)(x + (size_t)row * DIM);
        float4 v = xr[t];
        float s = v.x * v.x + v.y * v.y + v.z * v.z + v.w * v.w;
#pragma unroll
        for (int off = 32; off; off >>= 1) s += __shfl_down(s, off, 64);
        __shared__ float red[4];
        int lane = t & 63, w = t >> 6;
        if (lane == 0) red[w] = s;
        __syncthreads();
        float tot = red[0] + red[1] + red[2] + red[3];
        float scale = 32.0f / fmaxf(sqrtf(tot), EPS_F);   // sqrt(1024)=32
        float4 g = ((const float4*)gamma)[t];
        union { ushort4 u4; ushort us[4]; } o;
        o.us[0] = bf16_bits(v.x * scale * g.x);
        o.us[1] = bf16_bits(v.y * scale * g.y);
        o.us[2] = bf16_bits(v.z * scale * g.z);
        o.us[3] = bf16_bits(v.w * scale * g.w);
        ((ushort4*)(xn + (size_t)row * DIM))[t] = o.u4;
    } else if (blk < 19456) {
        int i = (blk - 16384) * 256 + t;          // n4 = 786432
        float4 v = ((const float4*)wq)[i];
        union { ushort4 u4; ushort us[4]; } o;
        o.us[0] = bf16_bits(v.x); o.us[1] = bf16_bits(v.y);
        o.us[2] = bf16_bits(v.z); o.us[3] = bf16_bits(v.w);
        ((ushort4*)wq_bf)[i] = o.u4;
    } else if (blk < 20480) {
        int i = (blk - 19456) * 256 + t;          // n4 = 262144
        float4 v = ((const float4*)wo)[i];
        union { ushort4 u4; ushort us[4]; } o;
        o.us[0] = bf16_bits(v.x); o.us[1] = bf16_bits(v.y);
        o.us[2] = bf16_bits(v.z); o.us[3] = bf16_bits(v.w);
        ((ushort4*)wo_bf)[i] = o.u4;
    } else {
        ss[(blk - 20480) * 256 + t] = 0.0f;
    }
}

// ---------------------------------------------------------------- 256x256x64 8-phase GEMM (T1+T2+T3+T5)
// C[m,o] = sum_k A[m,k]*W[o,k], A: Mx1024 bf16, W: Nx1024 bf16.
// 512 threads = 8 waves (2M x 4N); per-wave output 128x64 = acc[8][4].
// LDS 128 KiB: [buf][A(32KB) B(32KB)]; rows of 64 bf16 (128 B).
// XOR-swizzle byte ^= ((row&7)<<4): linear gload_lds dest + inverse-swizzled
// global source + swizzled ds_read (rule 21). Bank-conflict = 0 [measured R10].
// XCD swizzle: 8 consecutive A-panel groups per XCD (nwg%8==0, bijective).
// Epilogue: LDS-transpose -> per-thread 256B contiguous 16B stores (kills RMW fetch).
// MODE 0: qkv epilogue (q/k transposed scatter bf16, v -> vT[bh*4096+n][64])
// MODE 1: plain f32 row-major C (per-instruction stores already 64B-contiguous).
template<int MODE>
__global__ __launch_bounds__(512, 1) void k_gemm256(const bf16* __restrict__ A,
                                                    const bf16* __restrict__ W,
                                                    void* __restrict__ outp) {
    __shared__ short lds[65536];   // 128 KB
    char* ldsb = (char*)lds;
    const int t = threadIdx.x, lane = t & 63, wv = t >> 6;
    const int wm = wv >> 2, wn = wv & 3;

    // ---- XCD-aware bijective block remap (dispatch pos lid -> XCD lid%8)
    const int nwg = gridDim.x * gridDim.y;
    const int lid = blockIdx.y * gridDim.x + blockIdx.x;
    const int wg = (lid & 7) * (nwg >> 3) + (lid >> 3);
    const int tm = (wg / gridDim.x) * 256;
    const int tn = (wg % gridDim.x) * 256;
    const int NT = KDIM / 64;      // 16 K-tiles

    // ---- staging: round r covers tile rows [r*64 + wv*8, +8), lane l -> row +(l>>3)
    const int rowst = wv * 8 + (lane >> 3);
    const int srcxor = (((lane & 7) ^ (lane >> 3)) << 4);   // bytes within 128-B row
    const bf16* Asrc = A + (size_t)(tm + rowst) * KDIM;
    const bf16* Wsrc = W + (size_t)(tn + rowst) * KDIM;

#define STAGE(bufo_, kt_) do {                                                   \
    int k0_ = (kt_) * 64;                                                        \
    _Pragma("unroll")                                                            \
    for (int r_ = 0; r_ < 4; ++r_)                                               \
        gload_lds16((const char*)(Asrc + (size_t)r_ * 64 * KDIM + k0_) + srcxor, \
                    ldsb + (bufo_) + r_ * 8192 + wv * 1024);                     \
    _Pragma("unroll")                                                            \
    for (int r_ = 0; r_ < 4; ++r_)                                               \
        gload_lds16((const char*)(Wsrc + (size_t)r_ * 64 * KDIM + k0_) + srcxor, \
                    ldsb + (bufo_) + 32768 + r_ * 8192 + wv * 1024);             \
} while (0)

    // ---- ds_read offsets (bytes, excluding buf and mf/nf*2048)
    const int rxor = (lane & 7) << 4;
    int aoff[2], boff[2];
#pragma unroll
    for (int ks = 0; ks < 2; ++ks) {
        int cb = (ks * 64 + ((lane >> 4) << 4)) ^ rxor;
        aoff[ks] = (wm * 128 + (lane & 15)) * 128 + cb;
        boff[ks] = 32768 + (wn * 64 + (lane & 15)) * 128 + cb;
    }

    f32x4 acc[8][4] = {};
    bf16x8 af[8][2], bfr[4][2];

    STAGE(0, 0);
    asm volatile("s_waitcnt vmcnt(0)" ::: "memory");
    __syncthreads();

    for (int kt = 0; kt < NT; ++kt) {
        const int bufo = (kt & 1) << 16;
        // ---------------- phase 0: A mf0-3 + B nf0-1 reads, stage next tile
#pragma unroll
        for (int mf = 0; mf < 4; ++mf)
#pragma unroll
            for (int ks = 0; ks < 2; ++ks)
                af[mf][ks] = *(const bf16x8*)(ldsb + bufo + aoff[ks] + mf * 2048);
#pragma unroll
        for (int nf = 0; nf < 2; ++nf)
#pragma unroll
            for (int ks = 0; ks < 2; ++ks)
                bfr[nf][ks] = *(const bf16x8*)(ldsb + bufo + boff[ks] + nf * 2048);
        if (kt + 1 < NT) STAGE(bufo ^ 65536, kt + 1);
        __builtin_amdgcn_s_barrier();
        __builtin_amdgcn_s_setprio(1);
#pragma unroll
        for (int ks = 0; ks < 2; ++ks)
#pragma unroll
            for (int mf = 0; mf < 4; ++mf)
#pragma unroll
                for (int nf = 0; nf < 2; ++nf)
                    acc[mf][nf] = __builtin_amdgcn_mfma_f32_16x16x32_bf16(af[mf][ks], bfr[nf][ks], acc[mf][nf], 0, 0, 0);
        __builtin_amdgcn_s_setprio(0);
        __builtin_amdgcn_s_barrier();
        // ---------------- phase 1: A mf4-7 reads
#pragma unroll
        for (int mf = 4; mf < 8; ++mf)
#pragma unroll
            for (int ks = 0; ks < 2; ++ks)
                af[mf][ks] = *(const bf16x8*)(ldsb + bufo + aoff[ks] + mf * 2048);
        __builtin_amdgcn_s_barrier();
        __builtin_amdgcn_s_setprio(1);
#pragma unroll
        for (int ks = 0; ks < 2; ++ks)
#pragma unroll
            for (int mf = 4; mf < 8; ++mf)
#pragma unroll
                for (int nf = 0; nf < 2; ++nf)
                    acc[mf][nf] = __builtin_amdgcn_mfma_f32_16x16x32_bf16(af[mf][ks], bfr[nf][ks], acc[mf][nf], 0, 0, 0);
        __builtin_amdgcn_s_setprio(0);
        __builtin_amdgcn_s_barrier();
        // ---------------- phase 2: B nf2-3 reads
#pragma unroll
        for (int nf = 2; nf < 4; ++nf)
#pragma unroll
            for (int ks = 0; ks < 2; ++ks)
                bfr[nf][ks] = *(const bf16x8*)(ldsb + bufo + boff[ks] + nf * 2048);
        __builtin_amdgcn_s_barrier();
        __builtin_amdgcn_s_setprio(1);
#pragma unroll
        for (int ks = 0; ks < 2; ++ks)
#pragma unroll
            for (int mf = 0; mf < 4; ++mf)
#pragma unroll
                for (int nf = 2; nf < 4; ++nf)
                    acc[mf][nf] = __builtin_amdgcn_mfma_f32_16x16x32_bf16(af[mf][ks], bfr[nf][ks], acc[mf][nf], 0, 0, 0);
        __builtin_amdgcn_s_setprio(0);
        __builtin_amdgcn_s_barrier();
        // ---------------- phase 3: no reads; wait staging before swap
        __builtin_amdgcn_s_setprio(1);
#pragma unroll
        for (int ks = 0; ks < 2; ++ks)
#pragma unroll
            for (int mf = 4; mf < 8; ++mf)
#pragma unroll
                for (int nf = 2; nf < 4; ++nf)
                    acc[mf][nf] = __builtin_amdgcn_mfma_f32_16x16x32_bf16(af[mf][ks], bfr[nf][ks], acc[mf][nf], 0, 0, 0);
        __builtin_amdgcn_s_setprio(0);
        if (kt + 1 < NT) asm volatile("s_waitcnt vmcnt(0)" ::: "memory");
        __builtin_amdgcn_s_barrier();
    }
#undef STAGE

    // ---------------- epilogue. C/D frag: col(o)=lane&15, row(m)=(lane>>4)*4+reg
    const int b = tm >> 12;       // 4096 rows per batch; 256-tile never straddles
    const int tm4 = tm & (NN - 1);
    if (MODE == 0 && tn < 2048) {
        // q/k: LDS [o_local 0..255][m 256*2B], 16B-block XOR swizzle by (o&31)
        bf16* qkv = (bf16*)outp;
        __syncthreads();
#pragma unroll
        for (int mf = 0; mf < 8; ++mf) {
            int ml = wm * 128 + mf * 16 + ((lane >> 4) << 2);
#pragma unroll
            for (int nf = 0; nf < 4; ++nf) {
                int ol = wn * 64 + nf * 16 + (lane & 15);
                union { ushort us[4]; uint2 u2; } pk;
#pragma unroll
                for (int r = 0; r < 4; ++r) pk.us[r] = bf16_bits(acc[mf][nf][r]);
                *(uint2*)(ldsb + ol * 512 + ((ml * 2) ^ ((ol & 31) << 4))) = pk.u2;
            }
        }
        __syncthreads();
        const int ol = t & 255, half = t >> 8;
        int o = tn + ol;
        size_t rowg = (size_t)((o >> 10) * 4 + b) * 1024 + (o & 1023);
        bf16* dst = qkv + rowg * NN + tm4 + half * 128;
        const int swz = (ol & 31) << 4;
#pragma unroll
        for (int i = 0; i < 16; ++i) {
            int m0 = half * 128 + i * 8;
            uint4 v = *(const uint4*)(ldsb + ol * 512 + ((m0 * 2) ^ swz));
            *(uint4*)(dst + i * 8) = v;
        }
    } else if (MODE == 0) {
        // v: LDS [m_local 0..255][o 256*2B], 16B-block XOR swizzle by (m&31)
        bf16* vT = (bf16*)outp + (size_t)8192 * NN;   // layout [bh*4096+n][64]
        __syncthreads();
#pragma unroll
        for (int mf = 0; mf < 8; ++mf) {
            int mlb = wm * 128 + mf * 16 + ((lane >> 4) << 2);
#pragma unroll
            for (int nf = 0; nf < 4; ++nf) {
                int ol = wn * 64 + nf * 16 + (lane & 15);
#pragma unroll
                for (int r = 0; r < 4; ++r) {
                    int ml = mlb + r;
                    *(ushort*)(ldsb + ml * 512 + ((ol * 2) ^ ((ml & 31) << 4))) =
                        bf16_bits(acc[mf][nf][r]);
                }
            }
        }
        __syncthreads();
        const int ml = t & 255, half = t >> 8;
        const int tnb = tn & 1023;
        const int swz = (ml & 31) << 4;
#pragma unroll
        for (int i = 0; i < 16; ++i) {
            int o0 = half * 128 + i * 8;
            uint4 v = *(const uint4*)(ldsb + ml * 512 + ((o0 * 2) ^ swz));
            int hd = tnb + o0;
            bf16* dst = vT + ((size_t)(b * 16 + (hd >> 6)) * NN + tm4 + ml) * 64 + (hd & 63);
            *(uint4*)dst = v;
        }
    } else {
        float* out = (float*)outp;
#pragma unroll
        for (int mf = 0; mf < 8; ++mf) {
            int mg = tm + wm * 128 + mf * 16 + ((lane >> 4) << 2);
#pragma unroll
            for (int nf = 0; nf < 4; ++nf) {
                int o = tn + wn * 64 + nf * 16 + (lane & 15);
#pragma unroll
                for (int r = 0; r < 4; ++r)
                    out[(size_t)(mg + r) * DIN + o] = acc[mf][nf][r];
            }
        }
    }
}

// ---------------------------------------------------------------- kernel 5: sim partials via MFMA + fused row-norm ss
__global__ __launch_bounds__(256) void k_sim(const bf16* __restrict__ qkv,
                                             float* __restrict__ part,
                                             float* __restrict__ ss) {
    __shared__ short Ks[2][8192];   // 2 x 64 rows x 128 bf16 (16 KB each)
    const int chunk = blockIdx.x;   // 0..7, 512 n each
    const int bh = blockIdx.y;      // 0..63
    const int t = threadIdx.x, lane = t & 63, w = t >> 6;
    const bf16* qb = qkv + (size_t)(bh * 64) * NN;
    const bf16* kb = qkv + (size_t)(4096 + bh * 64) * NN;
    const int n0b = chunk * 512;

#define SIM_STAGE(buf, nt) do {                                              \
    int n0_ = n0b + (nt) * 128;                                              \
    _Pragma("unroll")                                                        \
    for (int cc = 0; cc < 4; ++cc) {                                         \
        int row_ = cc * 16 + (t >> 4);                                       \
        int colb_ = ((t & 15) << 4) ^ ((row_ & 7) << 4);                     \
        gload_lds16(kb + (size_t)row_ * NN + n0_ + (colb_ >> 1),             \
                    &Ks[buf][cc * 2048 + w * 512]);                          \
    }                                                                        \
} while (0)

    f32x4 acc[4] = {};
    float ssq = 0.f, ssk = 0.f;

    SIM_STAGE(0, 0);
    __syncthreads();
    for (int nt = 0; nt < 4; ++nt) {
        if (nt < 3) SIM_STAGE((nt + 1) & 1, nt + 1);
        {
            const int buf = nt & 1;
            const int n0 = n0b + nt * 128;
            bf16x8 af[4];
#pragma unroll
            for (int ks = 0; ks < 4; ++ks) {
                af[ks] = *(const bf16x8*)(qb + (size_t)(w * 16 + (lane & 15)) * NN +
                                          n0 + ks * 32 + ((lane >> 4) << 3));
#pragma unroll
                for (int i = 0; i < 8; ++i) { float f = b2f((ushort)af[ks][i]); ssq += f * f; }
            }
#pragma unroll
            for (int j = 0; j < 4; ++j) {
                int e = j * 16 + (lane & 15);
#pragma unroll
                for (int ks = 0; ks < 4; ++ks) {
                    bf16x8 bfr = *(const bf16x8*)((const char*)&Ks[buf][0] + e * 256 +
                                  ((ks * 64 + ((lane >> 4) << 4)) ^ ((e & 7) << 4)));
                    if (j == w) {
#pragma unroll
                        for (int i = 0; i < 8; ++i) { float f = b2f((ushort)bfr[i]); ssk += f * f; }
                    }
                    acc[j] = __builtin_amdgcn_mfma_f32_16x16x32_bf16(af[ks], bfr, acc[j], 0, 0, 0);
                }
            }
        }
        __syncthreads();
    }
#undef SIM_STAGE

    float vq = ssq; vq += __shfl_xor(vq, 16, 64); vq += __shfl_xor(vq, 32, 64);
    if (lane < 16) atomicAdd(&ss[bh * 64 + w * 16 + lane], vq);
    float vk = ssk; vk += __shfl_xor(vk, 16, 64); vk += __shfl_xor(vk, 32, 64);
    if (lane < 16) atomicAdd(&ss[4096 + bh * 64 + w * 16 + lane], vk);

    float* pb = part + (size_t)(bh * 8 + chunk) * 4096;
#pragma unroll
    for (int j = 0; j < 4; ++j) {
        int e = j * 16 + (lane & 15);
#pragma unroll
        for (int r = 0; r < 4; ++r) {
            int d = w * 16 + ((lane >> 4) << 2) + r;
            pb[d * 64 + e] = acc[j][r];
        }
    }
}

// ---------------------------------------------------------------- kernel 6: finalize + softmax -> bf16 attn[d][e]
__global__ __launch_bounds__(256) void k_softfin(const float* __restrict__ part,
                                                 const float* __restrict__ ss,
                                                 const float* __restrict__ temp,
                                                 bf16* __restrict__ attn) {
    int bh = blockIdx.x;
    int t = threadIdx.x, e = t & 63, w = t >> 6;
    float expT = __expf(temp[bh & (HEADS - 1)]);
    float ike = 8.0f * expT / fmaxf(sqrtf(ss[4096 + bh * 64 + e]), EPS_F);
    const float* pb = part + (size_t)bh * 8 * 4096;
#pragma unroll 2
    for (int dd = 0; dd < 16; ++dd) {
        int d = w * 16 + dd;
        float s = 0.f;
#pragma unroll
        for (int c = 0; c < 8; ++c) s += pb[c * 4096 + d * 64 + e];
        float invq = 1.0f / fmaxf(sqrtf(ss[bh * 64 + d]), EPS_F);
        float logit = s * ike * invq;
        float m = logit;
#pragma unroll
        for (int off = 32; off; off >>= 1) m = fmaxf(m, __shfl_xor(m, off, 64));
        float p = __expf(logit - m);
        float sum = p;
#pragma unroll
        for (int off = 32; off; off >>= 1) sum += __shfl_xor(sum, off, 64);
        attn[(size_t)bh * 4096 + d * 64 + e] = __float2bfloat16(p / sum);
    }
}

// ---------------------------------------------------------------- kernel 7: attn @ v via MFMA (no LDS, no barriers)
__global__ __launch_bounds__(256) void k_attnv(const bf16* __restrict__ qkv,
                                               const bf16* __restrict__ attn,
                                               bf16* __restrict__ A2) {
    const int nc = blockIdx.x;   // 0..15 (256 n each)
    const int bh = blockIdx.y;   // 0..63
    const int t = threadIdx.x, lane = t & 63, w = t >> 6;
    const bf16* vT = qkv + (size_t)8192 * NN + (size_t)bh * NN * 64;
    const bf16* ab = attn + (size_t)bh * 4096;
    const int nbase = nc * 256 + w * 64;

    bf16x8 bfr[4][2];
#pragma unroll
    for (int df = 0; df < 4; ++df)
#pragma unroll
        for (int ks = 0; ks < 2; ++ks)
            bfr[df][ks] = *(const bf16x8*)(ab + (df * 16 + (lane & 15)) * 64 +
                                           ks * 32 + ((lane >> 4) << 3));

    f32x4 acc[4][4] = {};
#pragma unroll
    for (int nf = 0; nf < 4; ++nf) {
#pragma unroll
        for (int ks = 0; ks < 2; ++ks) {
            bf16x8 af = *(const bf16x8*)(vT + (size_t)(nbase + nf * 16 + (lane & 15)) * 64 +
                                         ks * 32 + ((lane >> 4) << 3));
#pragma unroll
            for (int df = 0; df < 4; ++df)
                acc[nf][df] = __builtin_amdgcn_mfma_f32_16x16x32_bf16(af, bfr[df][ks], acc[nf][df], 0, 0, 0);
        }
    }
    const int b = bh >> 4, h = bh & 15;
#pragma unroll
    for (int nf = 0; nf < 4; ++nf)
#pragma unroll
        for (int df = 0; df < 4; ++df)
#pragma unroll
            for (int r = 0; r < 4; ++r) {
                int n = nbase + nf * 16 + ((lane >> 4) << 2) + r;
                int d = df * 16 + (lane & 15);
                A2[(size_t)(b * NN + n) * DIN + h * 64 + d] = __float2bfloat16(acc[nf][df][r]);
            }
}

// ---------------------------------------------------------------- launch
extern "C" void kernel_launch(void* const* d_in, const int* in_sizes, int n_in,
                              void* d_out, int out_size, void* d_ws, size_t ws_size,
                              hipStream_t stream) {
    const float* x      = (const float*)d_in[0];
    const float* gamma  = (const float*)d_in[1];
    const float* w_qkv  = (const float*)d_in[2];
    const float* temp   = (const float*)d_in[3];
    const float* w_out  = (const float*)d_in[4];
    float* out = (float*)d_out;

    char* ws = (char*)d_ws;
    // workspace layout (~152 MB)
    bf16*  qkv    = (bf16*)ws;                       // 3*4096*4096*2 = 100663296 (v region transposed)
    bf16*  xn     = (bf16*)(ws + 100663296);         // 16384*1024*2  =  33554432
    bf16*  wq_bf  = (bf16*)(ws + 134217728);         //  3072*1024*2  =   6291456
    bf16*  wo_bf  = (bf16*)(ws + 140509184);         //  1024*1024*2  =   2097152
    float* ss     = (float*)(ws + 142606336);        //  8192*4       =     32768
    float* part   = (float*)(ws + 142639104);        //  64*8*4096*4  =   8388608
    bf16*  attnw  = (bf16*)(ws + 151027712);         //  64*4096*2    =    524288

    k_prologue<<<20512, 256, 0, stream>>>(x, gamma, xn, w_qkv, wq_bf, w_out, wo_bf, ss);
    k_gemm256<0><<<dim3(NQO / 256, MTOT / 256), 512, 0, stream>>>(xn, wq_bf, (void*)qkv);
    k_sim<<<dim3(8, 64), 256, 0, stream>>>(qkv, part, ss);
    k_softfin<<<64, 256, 0, stream>>>(part, ss, temp, attnw);
    bf16* A2 = xn;  // xn is dead after GEMM1; reuse as attention-output buffer
    k_attnv<<<dim3(16, 64), 256, 0, stream>>>(qkv, attnw, A2);
    k_gemm256<1><<<dim3(DIN / 256, MTOT / 256), 512, 0, stream>>>(A2, wo_bf, (void*)out);
}